// Round 2
// baseline (9450.421 us; speedup 1.0000x reference)
//
#include <hip/hip_runtime.h>

typedef unsigned int u32;
typedef unsigned short u16;
typedef __attribute__((ext_vector_type(8))) short short8;
typedef __attribute__((ext_vector_type(4))) float f32x4;

#define SEQ 512
#define BATCH 32
#define DIM 1024
#define NB 128   // persistent blocks in recurrent kernel

// workspace layout (bytes)
#define OFF_XT    0ull                  // bf16 [16384][1024]  (row m = s*32+b)
#define OFF_UBT   33554432ull           // bf16 [4096][1024]   U^T concat (k_gemm B)
#define OFF_WG2   41943040ull           // bf16 [128 blk][32 ks][32 rr][32 kk] K-major tiled W
#define OFF_XPROJ 50331648ull           // bf16 [512][32][4096]
#define OFF_HBUF  184549376ull          // bf16 [2][32768] K-major tiled h
#define OFF_BIAS  184680448ull          // f32  [4096]
#define OFF_SYNC  184696832ull          // u32 arrive[128*16] (64B-padded flags)

__device__ __forceinline__ float bf2f(u16 u) {
  union { u32 u; float f; } v; v.u = ((u32)u) << 16; return v.f;
}
__device__ __forceinline__ u16 f2bf(float f) {
  union { float f; u32 u; } v; v.f = f;
  u32 r = v.u + 0x7FFFu + ((v.u >> 16) & 1u);
  return (u16)(r >> 16);
}
__device__ __forceinline__ void gload_lds16(const u16* g, u16* l) {
  __builtin_amdgcn_global_load_lds(
      (const __attribute__((address_space(1))) u32*)g,
      (__attribute__((address_space(3))) u32*)l, 16, 0, 0);
}

// ---------------- init: zero h buffers + flags, concat bias ---------------
__global__ void k_init(u32* hb, float* biasc, u32* sync,
                       const float* bi, const float* bfv,
                       const float* bo, const float* bg) {
  int i = blockIdx.x * 256 + threadIdx.x;
  if (i < 32768) {
    hb[i] = 0u;                       // both 64KB h buffers (128KB = 32768 u32)
  } else if (i < 32768 + 4096) {
    int e = i - 32768;
    int g = e >> 10, c = e & 1023;
    const float* p = (g == 0) ? bi : (g == 1) ? bfv : (g == 2) ? bo : bg;
    biasc[e] = p[c];
  } else if (i < 32768 + 4096 + 2048) {
    sync[i - 32768 - 4096] = 0u;      // 128 padded arrive flags
  }
}

// ---------------- transpose-cast the 8 weight matrices --------------------
// U matrices -> Ubt[e][k] row-major ([N][K] for k_gemm B operand)
// W matrices -> Wg2 K-major tiled per recurrent block:
//   off = blk*32768 + (k>>5)*1024 + rr*32 + (k&31),
//   rr = (gate<<3)|(c&7), blk = c>>3
__global__ void k_prep_w(const float* Ui, const float* Wi, const float* Uf,
                         const float* Wf, const float* Uo, const float* Wo,
                         const float* Ug, const float* Wg, u16* Ubt, u16* Wg2) {
  __shared__ float tile[64][65];
  int bx = blockIdx.x;
  int mi = bx >> 8;               // matrix 0..7 (Ui,Wi,Uf,Wf,Uo,Wo,Ug,Wg)
  int tt = bx & 255;
  int tr = tt >> 4, tc = tt & 15; // 16x16 grid of 64x64 tiles
  const float* src;
  switch (mi) {
    case 0: src = Ui; break; case 1: src = Wi; break;
    case 2: src = Uf; break; case 3: src = Wf; break;
    case 4: src = Uo; break; case 5: src = Wo; break;
    case 6: src = Ug; break; default: src = Wg; break;
  }
  int g = mi >> 1;
  int d0 = tr * 64, c0 = tc * 64;
  int ty = threadIdx.x >> 6, tx = threadIdx.x & 63;
#pragma unroll
  for (int i = 0; i < 16; ++i) {
    int r = i * 4 + ty;
    tile[r][tx] = src[(size_t)(d0 + r) * 1024 + c0 + tx];
  }
  __syncthreads();
  if (mi & 1) {
    // W matrix -> K-major tiled per-block slices
#pragma unroll
    for (int i = 0; i < 16; ++i) {
      int cc = i * 4 + ty;
      int c_full = c0 + cc;
      int k = d0 + tx;
      int blk = c_full >> 3;
      int rr = (g << 3) | (c_full & 7);
      Wg2[(size_t)blk * 32768 + ((k >> 5) << 10) + rr * 32 + (k & 31)] =
          f2bf(tile[tx][cc]);
    }
  } else {
    // U matrix -> [e][k] row-major
#pragma unroll
    for (int i = 0; i < 16; ++i) {
      int cc = i * 4 + ty;
      Ubt[(size_t)((g << 10) + c0 + cc) * 1024 + d0 + tx] = f2bf(tile[tx][cc]);
    }
  }
}

// ---------------- transpose-cast X: Xt[s*32+b][d] = X[b][s][d] ------------
__global__ void k_prep_x(const float* __restrict__ X, u16* __restrict__ Xt) {
  int idx = blockIdx.x * 256 + threadIdx.x;   // 4M threads, 4 elems each
  int m = idx >> 8, d4 = (idx & 255) << 2;
  int s = m >> 5, b = m & 31;
  const float4* p = (const float4*)(X + (size_t)(b * SEQ + s) * DIM + d4);
  float4 v = *p;
  u16 o[4] = { f2bf(v.x), f2bf(v.y), f2bf(v.z), f2bf(v.w) };
  *(ushort4*)(Xt + (size_t)m * DIM + d4) = *(ushort4*)o;
}

// ---------------- phase 1 GEMM: xproj = Xt @ U + bias  (m97 structure) ----
__global__ __launch_bounds__(256) void k_gemm(const u16* __restrict__ Xt,
                                              const u16* __restrict__ Ubt,
                                              const float* __restrict__ biasc,
                                              u16* __restrict__ xproj) {
  __shared__ u16 As[128 * 32];
  __shared__ u16 Bs[128 * 32];
  int tid = threadIdx.x;
  int w = tid >> 6, l = tid & 63;
  int n0 = blockIdx.x * 128, m0 = blockIdx.y * 128;
  int wm = w >> 1, wn = w & 1;
  int lrow = l & 15, lq = l >> 4;
  f32x4 acc[4][4] = {};
  for (int kt = 0; kt < 32; ++kt) {
    int k0 = kt * 32;
    __syncthreads();
#pragma unroll
    for (int is = 0; is < 2; ++is) {
      int c = is * 256 + w * 64 + l;
      int row = c >> 2, kg = c & 3;
      gload_lds16(Xt + (size_t)(m0 + row) * 1024 + k0 + kg * 8, As + c * 8);
      gload_lds16(Ubt + (size_t)(n0 + row) * 1024 + k0 + kg * 8, Bs + c * 8);
    }
    __syncthreads();
    short8 af[4], bf[4];
#pragma unroll
    for (int mt = 0; mt < 4; ++mt)
      af[mt] = *(const short8*)(As + (wm * 64 + mt * 16 + lrow) * 32 + lq * 8);
#pragma unroll
    for (int nt = 0; nt < 4; ++nt)
      bf[nt] = *(const short8*)(Bs + (wn * 64 + nt * 16 + lrow) * 32 + lq * 8);
#pragma unroll
    for (int mt = 0; mt < 4; ++mt)
#pragma unroll
      for (int nt = 0; nt < 4; ++nt)
        acc[mt][nt] = __builtin_amdgcn_mfma_f32_16x16x32_bf16(
            af[mt], bf[nt], acc[mt][nt], 0, 0, 0);
  }
#pragma unroll
  for (int nt = 0; nt < 4; ++nt) {
    int col = n0 + wn * 64 + nt * 16 + lrow;
    float bv = biasc[col];
#pragma unroll
    for (int mt = 0; mt < 4; ++mt) {
      int rbase = m0 + wm * 64 + mt * 16 + lq * 4;
#pragma unroll
      for (int r = 0; r < 4; ++r)
        xproj[(size_t)(rbase + r) * 4096 + col] = f2bf(acc[mt][nt][r] + bv);
    }
  }
}

// ---------------- phase 2: persistent recurrent kernel --------------------
// 128 blocks; block owns h-cols [blk*8, blk*8+8) -> z-cols e=(rr>>3)*1024+blk*8+(rr&7)
// h/W layouts are K-major tiled: off(r,k) = (k>>5)*1024 + r*32 + (k&31)
//   -> ds_read_b128 fragment reads hit 8 accesses/bank (wave64 minimum)
//   -> global_load_lds stays a pure linear copy (DMA-compatible)
__global__ __launch_bounds__(256, 1) void k_rec(const u16* __restrict__ Wg2,
                                                const u16* __restrict__ xproj,
                                                u16* hbuf, float* out, u32* sync) {
  __shared__ u16 Ws[32 * 1024];     // 64KB, staged once
  __shared__ u16 Hs[32 * 1024];     // 64KB, re-staged per step
  __shared__ u16 XPs[32 * 32];      // 2KB x_proj slice
  __shared__ float zbuf[32][33];    // 4.2KB z tile
  int tid = threadIdx.x;
  int w = tid >> 6, l = tid & 63;
  int blk = blockIdx.x;
  int lrow = l & 15, lq = l >> 4;
  // stage W slice once: linear 64KB copy (already in per-block tiled order)
#pragma unroll
  for (int it = 0; it < 16; ++it) {
    int c = it * 256 + w * 64 + l;
    gload_lds16(Wg2 + (size_t)blk * 32768 + c * 8, Ws + c * 8);
  }
  float c_reg = 0.f;
  int eb = tid >> 3, ec = tid & 7;  // epilogue: thread owns (batch eb, hcol ec)
  int mt = w >> 1, nt = w & 1;      // wave tile assignment
  int pollidx = (tid & 127) * 16;   // 2 threads per flag, 64B padded
  const u16* ap0 = Hs + (mt * 16 + lrow) * 32 + lq * 8;
  const u16* bp0 = Ws + (nt * 16 + lrow) * 32 + lq * 8;
  __syncthreads();

  for (int s = 0; s < SEQ; ++s) {
    // stage h_prev (linear 64KB) + x_proj slice
    const u16* hsrc = hbuf + (size_t)(s & 1) * 32768;
#pragma unroll
    for (int it = 0; it < 16; ++it) {
      int c = it * 256 + w * 64 + l;
      gload_lds16(hsrc + c * 8, Hs + c * 8);
    }
    if (w < 2) {
      int c2 = w * 64 + l;
      int b = c2 >> 2, g = c2 & 3;
      gload_lds16(xproj + (size_t)(s * 32 + b) * 4096 + (g << 10) + (blk << 3),
                  XPs + c2 * 8);
    }
    __syncthreads();

    // z = h_prev @ W_slice : wave (mt,nt) computes 16x16 tile
    f32x4 acc = { 0.f, 0.f, 0.f, 0.f };
#pragma unroll
    for (int ks = 0; ks < 32; ++ks) {
      short8 af = *(const short8*)(ap0 + ks * 1024);
      short8 bf = *(const short8*)(bp0 + ks * 1024);
      acc = __builtin_amdgcn_mfma_f32_16x16x32_bf16(af, bf, acc, 0, 0, 0);
    }
    {
      int col = nt * 16 + lrow;
      int rb = mt * 16 + lq * 4;
#pragma unroll
      for (int r = 0; r < 4; ++r) zbuf[rb + r][col] = acc[r];
    }
    __syncthreads();

    // gates: zbuf cols 0-7=i, 8-15=f, 16-23=o, 24-31=g
    float zi = zbuf[eb][ec]      + bf2f(XPs[eb * 32 + ec]);
    float zf = zbuf[eb][8 + ec]  + bf2f(XPs[eb * 32 + 8 + ec]);
    float zo = zbuf[eb][16 + ec] + bf2f(XPs[eb * 32 + 16 + ec]);
    float zg = zbuf[eb][24 + ec] + bf2f(XPs[eb * 32 + 24 + ec]);
    float ig = 1.f / (1.f + __expf(-zi));
    float fg = 1.f / (1.f + __expf(-zf));
    float og = 1.f / (1.f + __expf(-zo));
    float gg = tanhf(zg);
    c_reg = 1.f / (1.f + __expf(-(fg * c_reg + ig * gg)));  // nonstandard cell
    float h = tanhf(c_reg) * og;
    __builtin_nontemporal_store(
        h, out + (size_t)(eb * SEQ + s) * DIM + (blk << 3) + ec);
    // h store in K-major tiled layout: d = blk*8+ec
    u16* hdst = hbuf + (size_t)((s + 1) & 1) * 32768 +
                ((blk >> 2) << 10) + eb * 32 + ((blk & 3) << 3) + ec;
    __builtin_nontemporal_store(f2bf(h), hdst);
    __syncthreads();   // all h/out stores drained (per-wave vmcnt0)

    // distributed flag barrier: 1 padded flag per block, parallel poll
    if (tid == 0) {
      __threadfence();                       // wb dirty L2 -> device visible
      __hip_atomic_store(sync + blk * 16, (u32)(s + 1), __ATOMIC_RELEASE,
                         __HIP_MEMORY_SCOPE_AGENT);
    }
    {
      int guard = 0;
      while (__hip_atomic_load(sync + pollidx, __ATOMIC_RELAXED,
                               __HIP_MEMORY_SCOPE_AGENT) < (u32)(s + 1)) {
        if (++guard > 50000000) break;       // anti-hang bailout
      }
    }
    __syncthreads();                         // waves jointly cover all 128 flags
    __threadfence();                         // per-wave inv before next h loads
  }
}

// ---------------------------------------------------------------------------
extern "C" void kernel_launch(void* const* d_in, const int* in_sizes, int n_in,
                              void* d_out, int out_size, void* d_ws,
                              size_t ws_size, hipStream_t stream) {
  const float* X   = (const float*)d_in[0];
  const float* Ui  = (const float*)d_in[1];
  const float* Wi  = (const float*)d_in[2];
  const float* Uf  = (const float*)d_in[3];
  const float* Wf  = (const float*)d_in[4];
  const float* Uo  = (const float*)d_in[5];
  const float* Wo  = (const float*)d_in[6];
  const float* Ug  = (const float*)d_in[7];
  const float* Wg  = (const float*)d_in[8];
  const float* bi  = (const float*)d_in[9];
  const float* bfv = (const float*)d_in[10];
  const float* bo  = (const float*)d_in[11];
  const float* bg  = (const float*)d_in[12];
  char* ws = (char*)d_ws;
  u16* Xt      = (u16*)(ws + OFF_XT);
  u16* Ubt     = (u16*)(ws + OFF_UBT);
  u16* Wg2     = (u16*)(ws + OFF_WG2);
  u16* xproj   = (u16*)(ws + OFF_XPROJ);
  u16* hbuf    = (u16*)(ws + OFF_HBUF);
  float* biasc = (float*)(ws + OFF_BIAS);
  u32* sync    = (u32*)(ws + OFF_SYNC);
  float* out   = (float*)d_out;

  k_init<<<152, 256, 0, stream>>>((u32*)hbuf, biasc, sync, bi, bfv, bo, bg);
  k_prep_w<<<2048, 256, 0, stream>>>(Ui, Wi, Uf, Wf, Uo, Wo, Ug, Wg, Ubt, Wg2);
  k_prep_x<<<16384, 256, 0, stream>>>(X, Xt);
  k_gemm<<<dim3(32, 128), 256, 0, stream>>>(Xt, Ubt, biasc, xproj);
  k_rec<<<NB, 256, 0, stream>>>(Wg2, xproj, hbuf, out, sync);
}

// Round 3
// 2170.326 us; speedup vs baseline: 4.3544x; 4.3544x over previous
//
#include <hip/hip_runtime.h>

typedef unsigned int u32;
typedef unsigned short u16;
typedef __attribute__((ext_vector_type(8))) short short8;
typedef __attribute__((ext_vector_type(4))) float f32x4;

#define SEQ 512
#define BATCH 32
#define DIM 1024
#define NB 128   // persistent blocks in recurrent kernel

// workspace layout (bytes)
#define OFF_XT    0ull                  // bf16 [16384][1024]  (row m = s*32+b)
#define OFF_UBT   33554432ull           // bf16 [4096][1024]   U^T concat (k_gemm B)
#define OFF_WG2   41943040ull           // bf16 [128 blk][32 ks][32 rr][32 kk] K-major tiled W
#define OFF_XPROJ 50331648ull           // bf16 [512][32][4096]
#define OFF_HBUF  184549376ull          // bf16 [2][32768] K-major tiled h
#define OFF_BIAS  184680448ull          // f32  [4096]
#define OFF_SYNC  184696832ull          // u32 flags[128*32] (128B-padded)

__device__ __forceinline__ float bf2f(u16 u) {
  union { u32 u; float f; } v; v.u = ((u32)u) << 16; return v.f;
}
__device__ __forceinline__ u16 f2bf(float f) {
  union { float f; u32 u; } v; v.f = f;
  u32 r = v.u + 0x7FFFu + ((v.u >> 16) & 1u);
  return (u16)(r >> 16);
}
__device__ __forceinline__ void gload_lds16(const u16* g, u16* l) {
  __builtin_amdgcn_global_load_lds(
      (const __attribute__((address_space(1))) u32*)g,
      (__attribute__((address_space(3))) u32*)l, 16, 0, 0);
}
// LLC-coherent LDS-DMA: aux=17 = SC0|SC1 -> bypass L1+L2, read at LLC
__device__ __forceinline__ void gload_lds16_coh(const u16* g, u16* l) {
  __builtin_amdgcn_global_load_lds(
      (const __attribute__((address_space(1))) u32*)g,
      (__attribute__((address_space(3))) u32*)l, 16, 0, 17);
}

// ---------------- init: zero h buffers + flags, concat bias ---------------
__global__ void k_init(u32* hb, float* biasc, u32* sync,
                       const float* bi, const float* bfv,
                       const float* bo, const float* bg) {
  int i = blockIdx.x * 256 + threadIdx.x;
  if (i < 32768) {
    hb[i] = 0u;                       // both 64KB h buffers (128KB = 32768 u32)
  } else if (i < 32768 + 4096) {
    int e = i - 32768;
    int g = e >> 10, c = e & 1023;
    const float* p = (g == 0) ? bi : (g == 1) ? bfv : (g == 2) ? bo : bg;
    biasc[e] = p[c];
  } else if (i < 32768 + 4096 + 4096) {
    sync[i - 32768 - 4096] = 0u;      // 128 flags padded to 128B each
  }
}

// ---------------- transpose-cast the 8 weight matrices --------------------
// U matrices -> Ubt[e][k] row-major ([N][K] for k_gemm B operand)
// W matrices -> Wg2 K-major tiled per recurrent block:
//   off = blk*32768 + (k>>5)*1024 + rr*32 + (k&31),
//   rr = (gate<<3)|(c&7), blk = c>>3
__global__ void k_prep_w(const float* Ui, const float* Wi, const float* Uf,
                         const float* Wf, const float* Uo, const float* Wo,
                         const float* Ug, const float* Wg, u16* Ubt, u16* Wg2) {
  __shared__ float tile[64][65];
  int bx = blockIdx.x;
  int mi = bx >> 8;               // matrix 0..7 (Ui,Wi,Uf,Wf,Uo,Wo,Ug,Wg)
  int tt = bx & 255;
  int tr = tt >> 4, tc = tt & 15; // 16x16 grid of 64x64 tiles
  const float* src;
  switch (mi) {
    case 0: src = Ui; break; case 1: src = Wi; break;
    case 2: src = Uf; break; case 3: src = Wf; break;
    case 4: src = Uo; break; case 5: src = Wo; break;
    case 6: src = Ug; break; default: src = Wg; break;
  }
  int g = mi >> 1;
  int d0 = tr * 64, c0 = tc * 64;
  int ty = threadIdx.x >> 6, tx = threadIdx.x & 63;
#pragma unroll
  for (int i = 0; i < 16; ++i) {
    int r = i * 4 + ty;
    tile[r][tx] = src[(size_t)(d0 + r) * 1024 + c0 + tx];
  }
  __syncthreads();
  if (mi & 1) {
    // W matrix -> K-major tiled per-block slices
#pragma unroll
    for (int i = 0; i < 16; ++i) {
      int cc = i * 4 + ty;
      int c_full = c0 + cc;
      int k = d0 + tx;
      int blk = c_full >> 3;
      int rr = (g << 3) | (c_full & 7);
      Wg2[(size_t)blk * 32768 + ((k >> 5) << 10) + rr * 32 + (k & 31)] =
          f2bf(tile[tx][cc]);
    }
  } else {
    // U matrix -> [e][k] row-major
#pragma unroll
    for (int i = 0; i < 16; ++i) {
      int cc = i * 4 + ty;
      Ubt[(size_t)((g << 10) + c0 + cc) * 1024 + d0 + tx] = f2bf(tile[tx][cc]);
    }
  }
}

// ---------------- transpose-cast X: Xt[s*32+b][d] = X[b][s][d] ------------
__global__ void k_prep_x(const float* __restrict__ X, u16* __restrict__ Xt) {
  int idx = blockIdx.x * 256 + threadIdx.x;   // 4M threads, 4 elems each
  int m = idx >> 8, d4 = (idx & 255) << 2;
  int s = m >> 5, b = m & 31;
  const float4* p = (const float4*)(X + (size_t)(b * SEQ + s) * DIM + d4);
  float4 v = *p;
  u16 o[4] = { f2bf(v.x), f2bf(v.y), f2bf(v.z), f2bf(v.w) };
  *(ushort4*)(Xt + (size_t)m * DIM + d4) = *(ushort4*)o;
}

// ---------------- phase 1 GEMM: xproj = Xt @ U + bias  (m97 structure) ----
__global__ __launch_bounds__(256) void k_gemm(const u16* __restrict__ Xt,
                                              const u16* __restrict__ Ubt,
                                              const float* __restrict__ biasc,
                                              u16* __restrict__ xproj) {
  __shared__ u16 As[128 * 32];
  __shared__ u16 Bs[128 * 32];
  int tid = threadIdx.x;
  int w = tid >> 6, l = tid & 63;
  int n0 = blockIdx.x * 128, m0 = blockIdx.y * 128;
  int wm = w >> 1, wn = w & 1;
  int lrow = l & 15, lq = l >> 4;
  f32x4 acc[4][4] = {};
  for (int kt = 0; kt < 32; ++kt) {
    int k0 = kt * 32;
    __syncthreads();
#pragma unroll
    for (int is = 0; is < 2; ++is) {
      int c = is * 256 + w * 64 + l;
      int row = c >> 2, kg = c & 3;
      gload_lds16(Xt + (size_t)(m0 + row) * 1024 + k0 + kg * 8, As + c * 8);
      gload_lds16(Ubt + (size_t)(n0 + row) * 1024 + k0 + kg * 8, Bs + c * 8);
    }
    __syncthreads();
    short8 af[4], bf[4];
#pragma unroll
    for (int mt = 0; mt < 4; ++mt)
      af[mt] = *(const short8*)(As + (wm * 64 + mt * 16 + lrow) * 32 + lq * 8);
#pragma unroll
    for (int nt = 0; nt < 4; ++nt)
      bf[nt] = *(const short8*)(Bs + (wn * 64 + nt * 16 + lrow) * 32 + lq * 8);
#pragma unroll
    for (int mt = 0; mt < 4; ++mt)
#pragma unroll
      for (int nt = 0; nt < 4; ++nt)
        acc[mt][nt] = __builtin_amdgcn_mfma_f32_16x16x32_bf16(
            af[mt], bf[nt], acc[mt][nt], 0, 0, 0);
  }
#pragma unroll
  for (int nt = 0; nt < 4; ++nt) {
    int col = n0 + wn * 64 + nt * 16 + lrow;
    float bv = biasc[col];
#pragma unroll
    for (int mt = 0; mt < 4; ++mt) {
      int rbase = m0 + wm * 64 + mt * 16 + lq * 4;
#pragma unroll
      for (int r = 0; r < 4; ++r)
        xproj[(size_t)(rbase + r) * 4096 + col] = f2bf(acc[mt][nt][r] + bv);
    }
  }
}

// ---------------- phase 2: persistent recurrent kernel --------------------
// 128 blocks; block owns h-cols [blk*8, blk*8+8).
// Coherence protocol (NO __threadfence anywhere):
//   h stores  : relaxed agent-scope u16 atomics (write-through to LLC)
//   flag      : relaxed agent-scope store after __syncthreads (vmcnt0 drained)
//   h loads   : global_load_lds aux=17 (SC0|SC1) -> read at LLC, no stale L1/L2
// One-way producer flags replace the device barrier: flag[b]=s+1 implies block b
// finished READING h[s], so double-buffered hbuf has no WAR hazard.
__global__ __launch_bounds__(256, 1) void k_rec(const u16* __restrict__ Wg2,
                                                const u16* __restrict__ xproj,
                                                u16* hbuf, float* out, u32* sync) {
  __shared__ u16 Ws[32 * 1024];     // 64KB, staged once
  __shared__ u16 Hs[32 * 1024];     // 64KB, re-staged per step
  __shared__ u16 XPs[32 * 32];      // 2KB x_proj slice
  __shared__ float zbuf[32][33];    // 4.2KB z tile
  int tid = threadIdx.x;
  int w = tid >> 6, l = tid & 63;
  int blk = blockIdx.x;
  int lrow = l & 15, lq = l >> 4;
  // stage W slice once: linear 64KB copy (already in per-block tiled order)
#pragma unroll
  for (int it = 0; it < 16; ++it) {
    int c = it * 256 + w * 64 + l;
    gload_lds16(Wg2 + (size_t)blk * 32768 + c * 8, Ws + c * 8);
  }
  float c_reg = 0.f;
  int eb = tid >> 3, ec = tid & 7;  // epilogue: thread owns (batch eb, hcol ec)
  int mt = w >> 1, nt = w & 1;      // wave tile assignment
  const u16* ap0 = Hs + (mt * 16 + lrow) * 32 + lq * 8;
  const u16* bp0 = Ws + (nt * 16 + lrow) * 32 + lq * 8;
  // h store address (K-major tiled, d = blk*8+ec)
  u16* hst_base = hbuf + ((blk >> 2) << 10) + eb * 32 + ((blk & 3) << 3) + ec;
  float* out_base = out + (size_t)eb * SEQ * DIM + (blk << 3) + ec;
  __syncthreads();

  for (int s = 0; s < SEQ; ++s) {
    // stage h_prev (LLC-coherent DMA) + x_proj slice (plain, read-only)
    const u16* hsrc = hbuf + (size_t)(s & 1) * 32768;
#pragma unroll
    for (int it = 0; it < 16; ++it) {
      int c = it * 256 + w * 64 + l;
      gload_lds16_coh(hsrc + c * 8, Hs + c * 8);
    }
    if (w < 2) {
      int c2 = w * 64 + l;
      int b = c2 >> 2, g = c2 & 3;
      gload_lds16(xproj + (size_t)(s * 32 + b) * 4096 + (g << 10) + (blk << 3),
                  XPs + c2 * 8);
    }
    __syncthreads();                 // SYNC-D: LDS staged

    // z = h_prev @ W_slice : wave (mt,nt) computes 16x16 tile
    f32x4 acc = { 0.f, 0.f, 0.f, 0.f };
#pragma unroll
    for (int ks = 0; ks < 32; ++ks) {
      short8 af = *(const short8*)(ap0 + ks * 1024);
      short8 bf = *(const short8*)(bp0 + ks * 1024);
      acc = __builtin_amdgcn_mfma_f32_16x16x32_bf16(af, bf, acc, 0, 0, 0);
    }
    {
      int col = nt * 16 + lrow;
      int rb = mt * 16 + lq * 4;
#pragma unroll
      for (int r = 0; r < 4; ++r) zbuf[rb + r][col] = acc[r];
    }
    __syncthreads();                 // SYNC-A: zbuf ready

    // gates: zbuf cols 0-7=i, 8-15=f, 16-23=o, 24-31=g
    float zi = zbuf[eb][ec]      + bf2f(XPs[eb * 32 + ec]);
    float zf = zbuf[eb][8 + ec]  + bf2f(XPs[eb * 32 + 8 + ec]);
    float zo = zbuf[eb][16 + ec] + bf2f(XPs[eb * 32 + 16 + ec]);
    float zg = zbuf[eb][24 + ec] + bf2f(XPs[eb * 32 + 24 + ec]);
    float ig = 1.f / (1.f + __expf(-zi));
    float fg = 1.f / (1.f + __expf(-zf));
    float og = 1.f / (1.f + __expf(-zo));
    float gg = tanhf(zg);
    c_reg = 1.f / (1.f + __expf(-(fg * c_reg + ig * gg)));  // nonstandard cell
    float h = tanhf(c_reg) * og;
    __builtin_nontemporal_store(h, out_base + (size_t)s * DIM);
    // write-through h store (visible at LLC when vmcnt retires)
    __hip_atomic_store(hst_base + (size_t)(((s + 1) & 1)) * 32768, f2bf(h),
                       __ATOMIC_RELAXED, __HIP_MEMORY_SCOPE_AGENT);
    __syncthreads();                 // SYNC-B: all waves' h stores drained

    if (tid == 0)
      __hip_atomic_store(sync + blk * 32, (u32)(s + 1), __ATOMIC_RELAXED,
                         __HIP_MEMORY_SCOPE_AGENT);
    if (w == 0) {                    // wave0 polls: lane l covers flags l, l+64
      u32 tgt = (u32)(s + 1);
      int guard = 0;
      for (;;) {
        u32 a = __hip_atomic_load(sync + l * 32, __ATOMIC_RELAXED,
                                  __HIP_MEMORY_SCOPE_AGENT);
        u32 b = __hip_atomic_load(sync + (64 + l) * 32, __ATOMIC_RELAXED,
                                  __HIP_MEMORY_SCOPE_AGENT);
        if (a >= tgt && b >= tgt) break;
        __builtin_amdgcn_s_sleep(1);
        if (++guard > 20000000) break;   // anti-hang bailout
      }
    }
    asm volatile("" ::: "memory");   // no hoisting h loads above the poll
    __syncthreads();                 // SYNC-C: poll done, Hs/zbuf reusable
  }
}

// ---------------------------------------------------------------------------
extern "C" void kernel_launch(void* const* d_in, const int* in_sizes, int n_in,
                              void* d_out, int out_size, void* d_ws,
                              size_t ws_size, hipStream_t stream) {
  const float* X   = (const float*)d_in[0];
  const float* Ui  = (const float*)d_in[1];
  const float* Wi  = (const float*)d_in[2];
  const float* Uf  = (const float*)d_in[3];
  const float* Wf  = (const float*)d_in[4];
  const float* Uo  = (const float*)d_in[5];
  const float* Wo  = (const float*)d_in[6];
  const float* Ug  = (const float*)d_in[7];
  const float* Wg  = (const float*)d_in[8];
  const float* bi  = (const float*)d_in[9];
  const float* bfv = (const float*)d_in[10];
  const float* bo  = (const float*)d_in[11];
  const float* bg  = (const float*)d_in[12];
  char* ws = (char*)d_ws;
  u16* Xt      = (u16*)(ws + OFF_XT);
  u16* Ubt     = (u16*)(ws + OFF_UBT);
  u16* Wg2     = (u16*)(ws + OFF_WG2);
  u16* xproj   = (u16*)(ws + OFF_XPROJ);
  u16* hbuf    = (u16*)(ws + OFF_HBUF);
  float* biasc = (float*)(ws + OFF_BIAS);
  u32* sync    = (u32*)(ws + OFF_SYNC);
  float* out   = (float*)d_out;

  k_init<<<160, 256, 0, stream>>>((u32*)hbuf, biasc, sync, bi, bfv, bo, bg);
  k_prep_w<<<2048, 256, 0, stream>>>(Ui, Wi, Uf, Wf, Uo, Wo, Ug, Wg, Ubt, Wg2);
  k_prep_x<<<16384, 256, 0, stream>>>(X, Xt);
  k_gemm<<<dim3(32, 128), 256, 0, stream>>>(Xt, Ubt, biasc, xproj);
  k_rec<<<NB, 256, 0, stream>>>(Wg2, xproj, hbuf, out, sync);
}